// Round 3
// baseline (33328.662 us; speedup 1.0000x reference)
//
#include <hip/hip_runtime.h>

#define T_STEPS 19
#define NBATCH  65536
#define RNN     256
#define EMB     128
#define KDIM    384   // RNN + EMB
#define ROWB    768   // KDIM * 2 bytes (LDS row stride)

typedef __bf16 bf16x8 __attribute__((ext_vector_type(8)));
typedef float  f32x16 __attribute__((ext_vector_type(16)));

__device__ __forceinline__ unsigned short f2bf(float f) {
    unsigned u = __float_as_uint(f);
    u += 0x7fffu + ((u >> 16) & 1u);
    return (unsigned short)(u >> 16);
}
__device__ __forceinline__ float sigm_(float x) {
    return 1.0f / (1.0f + __expf(-x));
}
__device__ __forceinline__ float tanh_(float x) {
    // tanh(x) = 1 - 2/(exp(2x)+1); safe at both infinities, no clamp needed
    float e = __expf(2.0f * x);
    return 1.0f - 2.0f / (e + 1.0f);
}

// ---- prep kernels: repack weights into MFMA-fragment order (bf16) in d_ws ----
__global__ void prep_wcat(const float* __restrict__ Whh, const float* __restrict__ Wih,
                          unsigned short* __restrict__ dst) {
    int tid = blockIdx.x * 256 + threadIdx.x;   // 49152 total
    int l  = tid & 63;
    int G  = tid >> 6;
    int kk = G % 24;
    int wg = G / 24;            // w*4+g
    int w  = wg >> 2, g = wg & 3;
    int j  = g * 256 + w * 32 + (l & 31);
    int kb = kk * 16 + 8 * (l >> 5);
    unsigned short v[8];
#pragma unroll
    for (int e = 0; e < 8; ++e) {
        int k = kb + e;
        float f = (k < 256) ? Whh[j * 256 + k] : Wih[j * 128 + (k - 256)];
        v[e] = f2bf(f);
    }
    uint4 pk;
    pk.x = (unsigned)v[0] | ((unsigned)v[1] << 16);
    pk.y = (unsigned)v[2] | ((unsigned)v[3] << 16);
    pk.z = (unsigned)v[4] | ((unsigned)v[5] << 16);
    pk.w = (unsigned)v[6] | ((unsigned)v[7] << 16);
    ((uint4*)dst)[tid] = pk;
}

__global__ void prep_wout(const float* __restrict__ Wout, unsigned short* __restrict__ dst) {
    int tid = blockIdx.x * 256 + threadIdx.x;   // 1024 total
    if (tid >= 1024) return;
    int l  = tid & 63;
    int kk = tid >> 6;
    int q  = l & 31;
    int kb = kk * 16 + 8 * (l >> 5);
    unsigned short v[8];
#pragma unroll
    for (int e = 0; e < 8; ++e) {
        float f = (q < 5) ? Wout[q * 256 + kb + e] : 0.0f;
        v[e] = f2bf(f);
    }
    uint4 pk;
    pk.x = (unsigned)v[0] | ((unsigned)v[1] << 16);
    pk.y = (unsigned)v[2] | ((unsigned)v[3] << 16);
    pk.z = (unsigned)v[4] | ((unsigned)v[5] << 16);
    pk.w = (unsigned)v[6] | ((unsigned)v[7] << 16);
    ((uint4*)dst)[tid] = pk;
}

__global__ void prep_bias(const float* __restrict__ bih, const float* __restrict__ bhh,
                          float* __restrict__ dst) {
    int tid = blockIdx.x * 256 + threadIdx.x;
    if (tid < 1024) dst[tid] = bih[tid] + bhh[tid];
}

// ---- main persistent-over-T kernel: 1 block = 64 samples, 16 waves, 2 blocks/CU ----
__global__ __launch_bounds__(1024, 8)
void lstm_main(const float* __restrict__ x_in, const float* __restrict__ h_in,
               const float* __restrict__ c_in, const int* __restrict__ mask,
               const float* __restrict__ W_emb, const float* __restrict__ b_emb,
               const float* __restrict__ b_out,
               const unsigned short* __restrict__ wcat_fr,
               const unsigned short* __restrict__ wout_fr,
               const float* __restrict__ bias_g,
               float* __restrict__ out) {
    __shared__ unsigned short A_lds[64 * KDIM];   // 48 KB: [row][k] bf16, XOR-swizzled
    __shared__ int   m_lds[2][64];                // mask double-buffer

    const int tid   = threadIdx.x;
    const int lane  = tid & 63;
    const int w     = tid >> 6;        // wave 0..15
    const int wsub  = w >> 1;          // gate-unit block 0..7
    const int mt    = w & 1;           // M-tile (row half) 0/1
    const int base  = blockIdx.x * 64;
    const int col   = lane & 31;
    const int khalf = lane >> 5;       // 0/1
    const int ubase = wsub * 32 + col; // hidden unit this lane owns in gate tiles

    float h_reg[16], c_reg[16];        // fp32 state for this wave's 32-row tile

    // init: load h0/c0, write bf16 h into A_lds
#pragma unroll
    for (int r = 0; r < 16; ++r) {
        int row = mt * 32 + (r & 3) + 8 * (r >> 2) + 4 * khalf;
        float hv = h_in[(size_t)(base + row) * RNN + ubase];
        float cv = c_in[(size_t)(base + row) * RNN + ubase];
        h_reg[r] = hv;
        c_reg[r] = cv;
        int byte = row * ROWB + ubase * 2;
        byte ^= ((row & 7) << 4);
        A_lds[byte >> 1] = f2bf(hv);
    }

    float bias4[4];
#pragma unroll
    for (int g = 0; g < 4; ++g) bias4[g] = bias_g[g * 256 + ubase];
    const float bo = (col < 5) ? b_out[col] : 0.0f;

    const unsigned short* wf = wcat_fr + (size_t)wsub * (4 * 24 * 64 * 8);

    for (int t = 0; t < T_STEPS; ++t) {
        // ---- Phase A: e = relu(x @ W_emb + b_emb) -> A_lds k=256..383; mask -> LDS ----
        {
            int row = tid >> 4;            // 0..63
            int jb  = (tid & 15) * 8;      // 8 j's per thread
            const float* xp = x_in + ((size_t)t * NBATCH + base + row) * 2;
            float x0 = xp[0], x1 = xp[1];
#pragma unroll
            for (int jj = 0; jj < 8; jj += 2) {
                int j = jb + jj;
                float e0 = fmaxf(fmaf(x0, W_emb[j],     fmaf(x1, W_emb[128 + j],     b_emb[j])),     0.0f);
                float e1 = fmaxf(fmaf(x0, W_emb[j + 1], fmaf(x1, W_emb[128 + j + 1], b_emb[j + 1])), 0.0f);
                int byte = row * ROWB + 512 + 2 * j;
                byte ^= ((row & 7) << 4);
                *(unsigned int*)((char*)A_lds + byte) =
                    (unsigned)f2bf(e0) | ((unsigned)f2bf(e1) << 16);
            }
            if (tid < 64) m_lds[t & 1][tid] = mask[(size_t)t * NBATCH + base + tid];
        }
        __syncthreads();  // bar1: A_lds + mask ready

        // ---- Phase B: gates(this wave's 32 rows × 32 units × 4 gates) ----
        f32x16 acc[4];
#pragma unroll
        for (int g = 0; g < 4; ++g) {
            f32x16 z;
#pragma unroll
            for (int q = 0; q < 16; ++q) z[q] = bias4[g];
            acc[g] = z;
        }
#pragma unroll 2
        for (int kk = 0; kk < 24; ++kk) {
            int row0 = mt * 32 + col;
            int b0 = row0 * ROWB + kk * 32 + 16 * khalf; b0 ^= ((row0 & 7) << 4);
            bf16x8 a0 = *(const bf16x8*)((const char*)A_lds + b0);
#pragma unroll
            for (int g = 0; g < 4; ++g) {
                bf16x8 bfr = *(const bf16x8*)(wf + ((size_t)(g * 24 + kk) * 64 + lane) * 8);
                acc[g] = __builtin_amdgcn_mfma_f32_32x32x16_bf16(a0, bfr, acc[g], 0, 0, 0);
            }
        }
        __syncthreads();  // bar2: all A_lds reads done before h overwrite

        // ---- Phase C: elementwise LSTM update (fp32), h/c in regs ----
#pragma unroll
        for (int r = 0; r < 16; ++r) {
            int row = mt * 32 + (r & 3) + 8 * (r >> 2) + 4 * khalf;
            float iv = sigm_(acc[0][r]);
            float fv = sigm_(acc[1][r]);
            float gv = tanh_(acc[2][r]);
            float ov = sigm_(acc[3][r]);
            float cn = fmaf(fv, c_reg[r], iv * gv);
            float hn = ov * tanh_(cn);
            int m = m_lds[t & 1][row];
            if (m) { c_reg[r] = cn; h_reg[r] = hn; }
            int byte = row * ROWB + ubase * 2;
            byte ^= ((row & 7) << 4);
            A_lds[byte >> 1] = f2bf(h_reg[r]);
        }
        __syncthreads();  // bar3: new h visible

        // ---- Phase D: out = h @ Wout^T + b_out (waves 0,1; 32-col padded tile) ----
        // overlaps with next Phase A on waves 2..15 (disjoint LDS regions)
        if (w < 2) {
            f32x16 oacc;
#pragma unroll
            for (int q = 0; q < 16; ++q) oacc[q] = bo;
#pragma unroll
            for (int kk = 0; kk < 16; ++kk) {
                int row = w * 32 + col;
                int b0 = row * ROWB + kk * 32 + 16 * khalf; b0 ^= ((row & 7) << 4);
                bf16x8 a = *(const bf16x8*)((const char*)A_lds + b0);
                bf16x8 bfr = *(const bf16x8*)(wout_fr + ((size_t)kk * 64 + lane) * 8);
                oacc = __builtin_amdgcn_mfma_f32_32x32x16_bf16(a, bfr, oacc, 0, 0, 0);
            }
            if (col < 5) {
#pragma unroll
                for (int r = 0; r < 16; ++r) {
                    int row = w * 32 + (r & 3) + 8 * (r >> 2) + 4 * khalf;
                    int m = m_lds[t & 1][row];
                    out[((size_t)t * NBATCH + base + row) * 5 + col] = m ? oacc[r] : 0.0f;
                }
            }
        }
        // no barrier here: D reads h-region (k<256); next A writes e-region (k>=256)
        // and m_lds slot (t+1)&1 — disjoint. C(t+1)'s h-writes are behind bar1+bar2.
    }

    // ---- final states (fp32) ----
    float* hout = out + (size_t)T_STEPS * NBATCH * 5;
    float* cout = hout + (size_t)NBATCH * RNN;
#pragma unroll
    for (int r = 0; r < 16; ++r) {
        int row = mt * 32 + (r & 3) + 8 * (r >> 2) + 4 * khalf;
        hout[(size_t)(base + row) * RNN + ubase] = h_reg[r];
        cout[(size_t)(base + row) * RNN + ubase] = c_reg[r];
    }
}

extern "C" void kernel_launch(void* const* d_in, const int* in_sizes, int n_in,
                              void* d_out, int out_size, void* d_ws, size_t ws_size,
                              hipStream_t stream) {
    (void)in_sizes; (void)n_in; (void)out_size; (void)ws_size;
    const float* x_in = (const float*)d_in[0];
    const float* h0   = (const float*)d_in[1];
    const float* c0   = (const float*)d_in[2];
    const int*   mk   = (const int*)d_in[3];
    const float* Wemb = (const float*)d_in[4];
    const float* bemb = (const float*)d_in[5];
    const float* Wih  = (const float*)d_in[6];
    const float* bih  = (const float*)d_in[7];
    const float* Whh  = (const float*)d_in[8];
    const float* bhh  = (const float*)d_in[9];
    const float* Wout = (const float*)d_in[10];
    const float* bout = (const float*)d_in[11];

    unsigned short* wcat = (unsigned short*)d_ws;        // 393216 bf16 = 768 KB
    unsigned short* wouf = wcat + 393216;                // 8192 bf16
    float*          bsg  = (float*)(wouf + 8192);        // 1024 f32

    prep_wcat<<<192, 256, 0, stream>>>(Whh, Wih, wcat);
    prep_wout<<<4, 256, 0, stream>>>(Wout, wouf);
    prep_bias<<<4, 256, 0, stream>>>(bih, bhh, bsg);

    float* outp = (float*)d_out;
    lstm_main<<<1024, 1024, 0, stream>>>(x_in, h0, c0, mk, Wemb, bemb, bout,
                                         wcat, wouf, bsg, outp);
}

// Round 4
// 3460.334 us; speedup vs baseline: 9.6316x; 9.6316x over previous
//
#include <hip/hip_runtime.h>

#define T_STEPS 19
#define NBATCH  65536
#define RNN     256
#define EMB     128
#define KDIM    384   // RNN + EMB
#define ROWB    768   // KDIM * 2 bytes (LDS row stride)

typedef __bf16 bf16x8 __attribute__((ext_vector_type(8)));
typedef float  f32x16 __attribute__((ext_vector_type(16)));

__device__ __forceinline__ unsigned short f2bf(float f) {
    unsigned u = __float_as_uint(f);
    u += 0x7fffu + ((u >> 16) & 1u);
    return (unsigned short)(u >> 16);
}
__device__ __forceinline__ float sigm_(float x) {
    return 1.0f / (1.0f + __expf(-x));
}
__device__ __forceinline__ float tanh_(float x) {
    // tanh(x) = 1 - 2/(exp(2x)+1); safe at both infinities, no clamp needed
    float e = __expf(2.0f * x);
    return 1.0f - 2.0f / (e + 1.0f);
}

// ---- prep kernels: repack weights into MFMA-fragment order (bf16) in d_ws ----
__global__ void prep_wcat(const float* __restrict__ Whh, const float* __restrict__ Wih,
                          unsigned short* __restrict__ dst) {
    int tid = blockIdx.x * 256 + threadIdx.x;   // 49152 total
    int l  = tid & 63;
    int G  = tid >> 6;
    int kk = G % 24;
    int wg = G / 24;            // w*4+g
    int w  = wg >> 2, g = wg & 3;
    int j  = g * 256 + w * 32 + (l & 31);
    int kb = kk * 16 + 8 * (l >> 5);
    unsigned short v[8];
#pragma unroll
    for (int e = 0; e < 8; ++e) {
        int k = kb + e;
        float f = (k < 256) ? Whh[j * 256 + k] : Wih[j * 128 + (k - 256)];
        v[e] = f2bf(f);
    }
    uint4 pk;
    pk.x = (unsigned)v[0] | ((unsigned)v[1] << 16);
    pk.y = (unsigned)v[2] | ((unsigned)v[3] << 16);
    pk.z = (unsigned)v[4] | ((unsigned)v[5] << 16);
    pk.w = (unsigned)v[6] | ((unsigned)v[7] << 16);
    ((uint4*)dst)[tid] = pk;
}

__global__ void prep_wout(const float* __restrict__ Wout, unsigned short* __restrict__ dst) {
    int tid = blockIdx.x * 256 + threadIdx.x;   // 1024 total
    if (tid >= 1024) return;
    int l  = tid & 63;
    int kk = tid >> 6;
    int q  = l & 31;
    int kb = kk * 16 + 8 * (l >> 5);
    unsigned short v[8];
#pragma unroll
    for (int e = 0; e < 8; ++e) {
        float f = (q < 5) ? Wout[q * 256 + kb + e] : 0.0f;
        v[e] = f2bf(f);
    }
    uint4 pk;
    pk.x = (unsigned)v[0] | ((unsigned)v[1] << 16);
    pk.y = (unsigned)v[2] | ((unsigned)v[3] << 16);
    pk.z = (unsigned)v[4] | ((unsigned)v[5] << 16);
    pk.w = (unsigned)v[6] | ((unsigned)v[7] << 16);
    ((uint4*)dst)[tid] = pk;
}

__global__ void prep_bias(const float* __restrict__ bih, const float* __restrict__ bhh,
                          float* __restrict__ dst) {
    int tid = blockIdx.x * 256 + threadIdx.x;
    if (tid < 1024) dst[tid] = bih[tid] + bhh[tid];
}

// ---- main persistent-over-T kernel: 1 block = 64 samples, 16 waves ----
// launch_bounds(1024,4): 4 waves/SIMD => 128 regs/thread cap (VGPR+AGPR unified).
// acc = 64 AGPR; c state in LDS to keep VGPRs ~50; no spill.
__global__ __launch_bounds__(1024, 4)
void lstm_main(const float* __restrict__ x_in, const float* __restrict__ h_in,
               const float* __restrict__ c_in, const int* __restrict__ mask,
               const float* __restrict__ W_emb, const float* __restrict__ b_emb,
               const float* __restrict__ b_out,
               const unsigned short* __restrict__ wcat_fr,
               const unsigned short* __restrict__ wout_fr,
               const float* __restrict__ bias_g,
               float* __restrict__ out) {
    __shared__ unsigned short A_lds[64 * KDIM];   // 48 KB: [row][k] bf16, XOR-swizzled
    __shared__ float c_lds[64 * RNN];             // 64 KB: c state fp32
    __shared__ int   m_lds[2][64];                // mask double-buffer

    const int tid   = threadIdx.x;
    const int lane  = tid & 63;
    const int w     = tid >> 6;        // wave 0..15
    const int wsub  = w >> 1;          // gate-unit block 0..7
    const int mt    = w & 1;           // M-tile (row half) 0/1
    const int base  = blockIdx.x * 64;
    const int col   = lane & 31;
    const int khalf = lane >> 5;       // 0/1
    const int ubase = wsub * 32 + col; // hidden unit this lane owns in gate tiles

    float h_reg[16];                   // fp32 h state for this wave's 32-row tile

    // init: load h0/c0; h -> regs + A_lds(bf16); c -> c_lds(f32)
#pragma unroll
    for (int r = 0; r < 16; ++r) {
        int row = mt * 32 + (r & 3) + 8 * (r >> 2) + 4 * khalf;
        float hv = h_in[(size_t)(base + row) * RNN + ubase];
        float cv = c_in[(size_t)(base + row) * RNN + ubase];
        h_reg[r] = hv;
        c_lds[row * RNN + ubase] = cv;
        int byte = row * ROWB + ubase * 2;
        byte ^= ((row & 7) << 4);
        A_lds[byte >> 1] = f2bf(hv);
    }

    float bias4[4];
#pragma unroll
    for (int g = 0; g < 4; ++g) bias4[g] = bias_g[g * 256 + ubase];
    const float bo = (col < 5) ? b_out[col] : 0.0f;

    const unsigned short* wf = wcat_fr + (size_t)wsub * (4 * 24 * 64 * 8);

    for (int t = 0; t < T_STEPS; ++t) {
        // ---- Phase A: e = relu(x @ W_emb + b_emb) -> A_lds k=256..383; mask -> LDS ----
        {
            int row = tid >> 4;            // 0..63
            int jb  = (tid & 15) * 8;      // 8 j's per thread
            const float* xp = x_in + ((size_t)t * NBATCH + base + row) * 2;
            float x0 = xp[0], x1 = xp[1];
#pragma unroll
            for (int jj = 0; jj < 8; jj += 2) {
                int j = jb + jj;
                float e0 = fmaxf(fmaf(x0, W_emb[j],     fmaf(x1, W_emb[128 + j],     b_emb[j])),     0.0f);
                float e1 = fmaxf(fmaf(x0, W_emb[j + 1], fmaf(x1, W_emb[128 + j + 1], b_emb[j + 1])), 0.0f);
                int byte = row * ROWB + 512 + 2 * j;
                byte ^= ((row & 7) << 4);
                *(unsigned int*)((char*)A_lds + byte) =
                    (unsigned)f2bf(e0) | ((unsigned)f2bf(e1) << 16);
            }
            if (tid < 64) m_lds[t & 1][tid] = mask[(size_t)t * NBATCH + base + tid];
        }
        __syncthreads();  // bar1: A_lds + mask ready

        // ---- Phase B: gates(this wave's 32 rows × 32 units × 4 gates) ----
        f32x16 acc[4];
#pragma unroll
        for (int g = 0; g < 4; ++g) {
            f32x16 z;
#pragma unroll
            for (int q = 0; q < 16; ++q) z[q] = bias4[g];
            acc[g] = z;
        }
#pragma unroll 1
        for (int kk = 0; kk < 24; ++kk) {
            int row0 = mt * 32 + col;
            int b0 = row0 * ROWB + kk * 32 + 16 * khalf; b0 ^= ((row0 & 7) << 4);
            bf16x8 a0 = *(const bf16x8*)((const char*)A_lds + b0);
#pragma unroll
            for (int g = 0; g < 4; ++g) {
                bf16x8 bfr = *(const bf16x8*)(wf + ((size_t)(g * 24 + kk) * 64 + lane) * 8);
                acc[g] = __builtin_amdgcn_mfma_f32_32x32x16_bf16(a0, bfr, acc[g], 0, 0, 0);
            }
        }
        __syncthreads();  // bar2: all A_lds reads done before h overwrite

        // ---- Phase C: elementwise LSTM update (fp32); c in LDS, h in regs ----
#pragma unroll
        for (int r = 0; r < 16; ++r) {
            int row = mt * 32 + (r & 3) + 8 * (r >> 2) + 4 * khalf;
            float cv = c_lds[row * RNN + ubase];
            float iv = sigm_(acc[0][r]);
            float fv = sigm_(acc[1][r]);
            float gv = tanh_(acc[2][r]);
            float ov = sigm_(acc[3][r]);
            float cn = fmaf(fv, cv, iv * gv);
            float hn = ov * tanh_(cn);
            int m = m_lds[t & 1][row];
            if (m) {
                c_lds[row * RNN + ubase] = cn;
                h_reg[r] = hn;
            }
            int byte = row * ROWB + ubase * 2;
            byte ^= ((row & 7) << 4);
            A_lds[byte >> 1] = f2bf(h_reg[r]);
        }
        __syncthreads();  // bar3: new h visible

        // ---- Phase D: out = h @ Wout^T + b_out (waves 0,1; 32-col padded tile) ----
        // overlaps with next Phase A on waves 2..15 (disjoint LDS regions)
        if (w < 2) {
            f32x16 oacc;
#pragma unroll
            for (int q = 0; q < 16; ++q) oacc[q] = bo;
#pragma unroll
            for (int kk = 0; kk < 16; ++kk) {
                int row = w * 32 + col;
                int b0 = row * ROWB + kk * 32 + 16 * khalf; b0 ^= ((row & 7) << 4);
                bf16x8 a = *(const bf16x8*)((const char*)A_lds + b0);
                bf16x8 bfr = *(const bf16x8*)(wout_fr + ((size_t)kk * 64 + lane) * 8);
                oacc = __builtin_amdgcn_mfma_f32_32x32x16_bf16(a, bfr, oacc, 0, 0, 0);
            }
            if (col < 5) {
#pragma unroll
                for (int r = 0; r < 16; ++r) {
                    int row = w * 32 + (r & 3) + 8 * (r >> 2) + 4 * khalf;
                    int m = m_lds[t & 1][row];
                    out[((size_t)t * NBATCH + base + row) * 5 + col] = m ? oacc[r] : 0.0f;
                }
            }
        }
        // no barrier here: D reads h-region (k<256); next A writes e-region (k>=256)
        // and m_lds slot (t+1)&1 — disjoint. C(t+1)'s h-writes are behind bar1+bar2.
    }

    // ---- final states (fp32) ----
    float* hout = out + (size_t)T_STEPS * NBATCH * 5;
    float* cout = hout + (size_t)NBATCH * RNN;
#pragma unroll
    for (int r = 0; r < 16; ++r) {
        int row = mt * 32 + (r & 3) + 8 * (r >> 2) + 4 * khalf;
        hout[(size_t)(base + row) * RNN + ubase] = h_reg[r];
        cout[(size_t)(base + row) * RNN + ubase] = c_lds[row * RNN + ubase];
    }
}

extern "C" void kernel_launch(void* const* d_in, const int* in_sizes, int n_in,
                              void* d_out, int out_size, void* d_ws, size_t ws_size,
                              hipStream_t stream) {
    (void)in_sizes; (void)n_in; (void)out_size; (void)ws_size;
    const float* x_in = (const float*)d_in[0];
    const float* h0   = (const float*)d_in[1];
    const float* c0   = (const float*)d_in[2];
    const int*   mk   = (const int*)d_in[3];
    const float* Wemb = (const float*)d_in[4];
    const float* bemb = (const float*)d_in[5];
    const float* Wih  = (const float*)d_in[6];
    const float* bih  = (const float*)d_in[7];
    const float* Whh  = (const float*)d_in[8];
    const float* bhh  = (const float*)d_in[9];
    const float* Wout = (const float*)d_in[10];
    const float* bout = (const float*)d_in[11];

    unsigned short* wcat = (unsigned short*)d_ws;        // 393216 bf16 = 768 KB
    unsigned short* wouf = wcat + 393216;                // 8192 bf16
    float*          bsg  = (float*)(wouf + 8192);        // 1024 f32

    prep_wcat<<<192, 256, 0, stream>>>(Whh, Wih, wcat);
    prep_wout<<<4, 256, 0, stream>>>(Wout, wouf);
    prep_bias<<<4, 256, 0, stream>>>(bih, bhh, bsg);

    float* outp = (float*)d_out;
    lstm_main<<<1024, 1024, 0, stream>>>(x_in, h0, c0, mk, Wemb, bemb, bout,
                                         wcat, wouf, bsg, outp);
}

// Round 5
// 2954.134 us; speedup vs baseline: 11.2820x; 1.1714x over previous
//
#include <hip/hip_runtime.h>

#define T_STEPS 19
#define NBATCH  65536
#define RNN     256
#define EMB     128
#define KDIM    384   // RNN + EMB
#define ROWB    768   // KDIM * 2 bytes (LDS row stride)

typedef __bf16 bf16x8 __attribute__((ext_vector_type(8)));
typedef float  f32x16 __attribute__((ext_vector_type(16)));

#define GLB(p) ((const __attribute__((address_space(1))) void*)(p))
#define LDS(p) ((__attribute__((address_space(3))) void*)(p))

__device__ __forceinline__ unsigned short f2bf(float f) {
    unsigned u = __float_as_uint(f);
    u += 0x7fffu + ((u >> 16) & 1u);
    return (unsigned short)(u >> 16);
}
__device__ __forceinline__ float sigm_(float x) {
    return 1.0f / (1.0f + __expf(-x));
}
__device__ __forceinline__ float tanh_(float x) {
    float e = __expf(2.0f * x);
    return 1.0f - 2.0f / (e + 1.0f);
}

// ---- prep: repack Wcat into kk-major fragment order ----
// dst uint4 index = (kk*32 + wsub*4 + g)*64 + l ; covers j = g*256+wsub*32+(l&31),
// k = kk*16 + 8*(l>>5) + e.  One kk-slice = 32 KB contiguous.
__global__ void prep_wcat(const float* __restrict__ Whh, const float* __restrict__ Wih,
                          unsigned short* __restrict__ dst) {
    int tid = blockIdx.x * 256 + threadIdx.x;   // 49152 total
    int l  = tid & 63;
    int p  = tid >> 6;          // 0..767
    int g    = p & 3;
    int wsub = (p >> 2) & 7;
    int kk   = p >> 5;          // 0..23
    int j  = g * 256 + wsub * 32 + (l & 31);
    int kb = kk * 16 + 8 * (l >> 5);
    unsigned short v[8];
#pragma unroll
    for (int e = 0; e < 8; ++e) {
        int k = kb + e;
        float f = (k < 256) ? Whh[j * 256 + k] : Wih[j * 128 + (k - 256)];
        v[e] = f2bf(f);
    }
    uint4 pk;
    pk.x = (unsigned)v[0] | ((unsigned)v[1] << 16);
    pk.y = (unsigned)v[2] | ((unsigned)v[3] << 16);
    pk.z = (unsigned)v[4] | ((unsigned)v[5] << 16);
    pk.w = (unsigned)v[6] | ((unsigned)v[7] << 16);
    ((uint4*)dst)[tid] = pk;
}

__global__ void prep_wout(const float* __restrict__ Wout, unsigned short* __restrict__ dst) {
    int tid = blockIdx.x * 256 + threadIdx.x;   // 1024 total
    if (tid >= 1024) return;
    int l  = tid & 63;
    int kk = tid >> 6;
    int q  = l & 31;
    int kb = kk * 16 + 8 * (l >> 5);
    unsigned short v[8];
#pragma unroll
    for (int e = 0; e < 8; ++e) {
        float f = (q < 5) ? Wout[q * 256 + kb + e] : 0.0f;
        v[e] = f2bf(f);
    }
    uint4 pk;
    pk.x = (unsigned)v[0] | ((unsigned)v[1] << 16);
    pk.y = (unsigned)v[2] | ((unsigned)v[3] << 16);
    pk.z = (unsigned)v[4] | ((unsigned)v[5] << 16);
    pk.w = (unsigned)v[6] | ((unsigned)v[7] << 16);
    ((uint4*)dst)[tid] = pk;
}

__global__ void prep_bias(const float* __restrict__ bih, const float* __restrict__ bhh,
                          float* __restrict__ dst) {
    int tid = blockIdx.x * 256 + threadIdx.x;
    if (tid < 1024) dst[tid] = bih[tid] + bhh[tid];
}

// ---- main persistent-over-T kernel: 1 block = 64 samples, 16 waves, 1 block/CU ----
// Weights stream global -> LDS via 3-deep global_load_lds pipeline (counted vmcnt).
__global__ __launch_bounds__(1024, 4)
void lstm_main(const float* __restrict__ x_in, const float* __restrict__ h_in,
               const float* __restrict__ c_in, const int* __restrict__ mask,
               const float* __restrict__ W_emb, const float* __restrict__ b_emb,
               const float* __restrict__ b_out,
               const unsigned short* __restrict__ wcat_fr,
               const unsigned short* __restrict__ wout_fr,
               const float* __restrict__ bias_g,
               float* __restrict__ out) {
    __shared__ unsigned short A_lds[64 * KDIM];       // 48 KB, XOR-swizzled
    __shared__ char wbuf[3 * 32768] __attribute__((aligned(16)));  // 96 KB weight pipeline
    __shared__ int   m_lds[2][64];

    const int tid   = threadIdx.x;
    const int lane  = tid & 63;
    const int w     = tid >> 6;        // wave 0..15
    const int wsub  = w >> 1;          // unit-block 0..7
    const int mt    = w & 1;           // M-tile 0/1
    const int base  = blockIdx.x * 64;
    const int col   = lane & 31;
    const int khalf = lane >> 5;
    const int ubase = wsub * 32 + col;

    float h_reg[16], c_reg[16];

#pragma unroll
    for (int r = 0; r < 16; ++r) {
        int row = mt * 32 + (r & 3) + 8 * (r >> 2) + 4 * khalf;
        float hv = h_in[(size_t)(base + row) * RNN + ubase];
        float cv = c_in[(size_t)(base + row) * RNN + ubase];
        h_reg[r] = hv;
        c_reg[r] = cv;
        int byte = row * ROWB + ubase * 2;
        byte ^= ((row & 7) << 4);
        A_lds[byte >> 1] = f2bf(hv);
    }

    float bias4[4];
#pragma unroll
    for (int g = 0; g < 4; ++g) bias4[g] = bias_g[g * 256 + ubase];
    const float bo = (col < 5) ? b_out[col] : 0.0f;

    // weight-pipeline lane pointers (each wave copies slices 2w, 2w+1 of each 32KB kk-slice)
    const char* wsrc = (const char*)wcat_fr + (size_t)(w * 2) * 1024 + (size_t)lane * 16;
    char*       wdst = wbuf + (size_t)(w * 2) * 1024;

    // prologue: issue kk=0 -> buf0, kk=1 -> buf1
    __builtin_amdgcn_global_load_lds(GLB(wsrc),                 LDS(wdst),                 16, 0, 0);
    __builtin_amdgcn_global_load_lds(GLB(wsrc + 1024),          LDS(wdst + 1024),          16, 0, 0);
    __builtin_amdgcn_global_load_lds(GLB(wsrc + 32768),         LDS(wdst + 32768),         16, 0, 0);
    __builtin_amdgcn_global_load_lds(GLB(wsrc + 32768 + 1024),  LDS(wdst + 32768 + 1024),  16, 0, 0);

    for (int t = 0; t < T_STEPS; ++t) {
        // ---- Phase A: e = relu(x @ W_emb + b_emb) -> A_lds k=256..383; mask -> LDS ----
        {
            int row = tid >> 4;
            int jb  = (tid & 15) * 8;
            const float* xp = x_in + ((size_t)t * NBATCH + base + row) * 2;
            float x0 = xp[0], x1 = xp[1];
#pragma unroll
            for (int jj = 0; jj < 8; jj += 2) {
                int j = jb + jj;
                float e0 = fmaxf(fmaf(x0, W_emb[j],     fmaf(x1, W_emb[128 + j],     b_emb[j])),     0.0f);
                float e1 = fmaxf(fmaf(x0, W_emb[j + 1], fmaf(x1, W_emb[128 + j + 1], b_emb[j + 1])), 0.0f);
                int byte = row * ROWB + 512 + 2 * j;
                byte ^= ((row & 7) << 4);
                *(unsigned int*)((char*)A_lds + byte) =
                    (unsigned)f2bf(e0) | ((unsigned)f2bf(e1) << 16);
            }
            if (tid < 64) m_lds[t & 1][tid] = mask[(size_t)t * NBATCH + base + tid];
        }
        __syncthreads();  // bar1: A_lds + mask ready (drains vmcnt; buffers 0,1 landed)

        // ---- Phase B: 24-phase pipelined gates ----
        f32x16 acc[4];
#pragma unroll
        for (int g = 0; g < 4; ++g) {
            f32x16 z;
#pragma unroll
            for (int q = 0; q < 16; ++q) z[q] = bias4[g];
            acc[g] = z;
        }
        int bufR = 0, bufW = 2;
#pragma unroll 1
        for (int kk = 0; kk < 24; ++kk) {
            // my kk-loads landed (2 newer outstanding: kk+1's); then block-wide sync
            asm volatile("s_waitcnt vmcnt(2)" ::: "memory");
            __builtin_amdgcn_s_barrier();
            asm volatile("" ::: "memory");
            // issue kk+2 (wraps to next step's kk0/kk1 — weights identical each step)
            int kkn = (kk + 2 < 24) ? (kk + 2) : (kk - 22);
            const char* s0 = wsrc + (size_t)kkn * 32768;
            char*       d0 = wdst + bufW * 32768;
            __builtin_amdgcn_global_load_lds(GLB(s0),        LDS(d0),        16, 0, 0);
            __builtin_amdgcn_global_load_lds(GLB(s0 + 1024), LDS(d0 + 1024), 16, 0, 0);
            // consume kk from wbuf[bufR]
            int row0 = mt * 32 + col;
            int b0 = row0 * ROWB + kk * 32 + 16 * khalf; b0 ^= ((row0 & 7) << 4);
            bf16x8 a0 = *(const bf16x8*)((const char*)A_lds + b0);
            const char* wb = wbuf + bufR * 32768 + wsub * 4096 + (size_t)lane * 16;
            bf16x8 f0 = *(const bf16x8*)(wb);
            bf16x8 f1 = *(const bf16x8*)(wb + 1024);
            bf16x8 f2 = *(const bf16x8*)(wb + 2048);
            bf16x8 f3 = *(const bf16x8*)(wb + 3072);
            acc[0] = __builtin_amdgcn_mfma_f32_32x32x16_bf16(a0, f0, acc[0], 0, 0, 0);
            acc[1] = __builtin_amdgcn_mfma_f32_32x32x16_bf16(a0, f1, acc[1], 0, 0, 0);
            acc[2] = __builtin_amdgcn_mfma_f32_32x32x16_bf16(a0, f2, acc[2], 0, 0, 0);
            acc[3] = __builtin_amdgcn_mfma_f32_32x32x16_bf16(a0, f3, acc[3], 0, 0, 0);
            bufR = (bufR == 2) ? 0 : bufR + 1;
            bufW = (bufW == 2) ? 0 : bufW + 1;
        }
        __syncthreads();  // bar2: all A_lds reads done; next-step w-prefetch drains here

        // ---- Phase C: elementwise LSTM update (fp32, regs) ----
#pragma unroll
        for (int r = 0; r < 16; ++r) {
            int row = mt * 32 + (r & 3) + 8 * (r >> 2) + 4 * khalf;
            float iv = sigm_(acc[0][r]);
            float fv = sigm_(acc[1][r]);
            float gv = tanh_(acc[2][r]);
            float ov = sigm_(acc[3][r]);
            float cn = fmaf(fv, c_reg[r], iv * gv);
            float hn = ov * tanh_(cn);
            int m = m_lds[t & 1][row];
            if (m) { c_reg[r] = cn; h_reg[r] = hn; }
            int byte = row * ROWB + ubase * 2;
            byte ^= ((row & 7) << 4);
            A_lds[byte >> 1] = f2bf(h_reg[r]);
        }
        __syncthreads();  // bar3: new h visible

        // ---- Phase D: out = h @ Wout^T + b_out (waves 0,1) ----
        if (w < 2) {
            f32x16 oacc;
#pragma unroll
            for (int q = 0; q < 16; ++q) oacc[q] = bo;
#pragma unroll
            for (int kk = 0; kk < 16; ++kk) {
                int row = w * 32 + col;
                int b0 = row * ROWB + kk * 32 + 16 * khalf; b0 ^= ((row & 7) << 4);
                bf16x8 a = *(const bf16x8*)((const char*)A_lds + b0);
                bf16x8 bfr = *(const bf16x8*)(wout_fr + ((size_t)kk * 64 + lane) * 8);
                oacc = __builtin_amdgcn_mfma_f32_32x32x16_bf16(a, bfr, oacc, 0, 0, 0);
            }
            if (col < 5) {
#pragma unroll
                for (int r = 0; r < 16; ++r) {
                    int row = w * 32 + (r & 3) + 8 * (r >> 2) + 4 * khalf;
                    int m = m_lds[t & 1][row];
                    out[((size_t)t * NBATCH + base + row) * 5 + col] = m ? oacc[r] : 0.0f;
                }
            }
        }
        // no barrier: D reads h-region (k<256); next A writes e-region + other m_lds slot
    }

    asm volatile("s_waitcnt vmcnt(0)" ::: "memory");  // retire any in-flight prefetch

    float* hout = out + (size_t)T_STEPS * NBATCH * 5;
    float* cout = hout + (size_t)NBATCH * RNN;
#pragma unroll
    for (int r = 0; r < 16; ++r) {
        int row = mt * 32 + (r & 3) + 8 * (r >> 2) + 4 * khalf;
        hout[(size_t)(base + row) * RNN + ubase] = h_reg[r];
        cout[(size_t)(base + row) * RNN + ubase] = c_reg[r];
    }
}

extern "C" void kernel_launch(void* const* d_in, const int* in_sizes, int n_in,
                              void* d_out, int out_size, void* d_ws, size_t ws_size,
                              hipStream_t stream) {
    (void)in_sizes; (void)n_in; (void)out_size; (void)ws_size;
    const float* x_in = (const float*)d_in[0];
    const float* h0   = (const float*)d_in[1];
    const float* c0   = (const float*)d_in[2];
    const int*   mk   = (const int*)d_in[3];
    const float* Wemb = (const float*)d_in[4];
    const float* bemb = (const float*)d_in[5];
    const float* Wih  = (const float*)d_in[6];
    const float* bih  = (const float*)d_in[7];
    const float* Whh  = (const float*)d_in[8];
    const float* bhh  = (const float*)d_in[9];
    const float* Wout = (const float*)d_in[10];
    const float* bout = (const float*)d_in[11];

    unsigned short* wcat = (unsigned short*)d_ws;        // 393216 bf16 = 768 KB (kk-major)
    unsigned short* wouf = wcat + 393216;                // 8192 bf16
    float*          bsg  = (float*)(wouf + 8192);        // 1024 f32

    prep_wcat<<<192, 256, 0, stream>>>(Whh, Wih, wcat);
    prep_wout<<<4, 256, 0, stream>>>(Wout, wouf);
    prep_bias<<<4, 256, 0, stream>>>(bih, bhh, bsg);

    float* outp = (float*)d_out;
    lstm_main<<<1024, 1024, 0, stream>>>(x_in, h0, c0, mk, Wemb, bemb, bout,
                                         wcat, wouf, bsg, outp);
}

// Round 6
// 2330.066 us; speedup vs baseline: 14.3037x; 1.2678x over previous
//
#include <hip/hip_runtime.h>

#define T_STEPS 19
#define NBATCH  65536
#define RNN     256
#define EMB     128
#define KDIM    384   // RNN + EMB
#define ROWB    768   // KDIM * 2 bytes (LDS row stride)
#define SWZ(row) (((row) & 15) << 4)

typedef __bf16 bf16x8 __attribute__((ext_vector_type(8)));
typedef float  f32x16 __attribute__((ext_vector_type(16)));

#define GLB(p) ((const __attribute__((address_space(1))) void*)(p))
#define LDS(p) ((__attribute__((address_space(3))) void*)(p))
#define BLOCK_SYNC() asm volatile("s_waitcnt lgkmcnt(0)\n\ts_barrier" ::: "memory")

__device__ __forceinline__ unsigned short f2bf(float f) {
    unsigned u = __float_as_uint(f);
    u += 0x7fffu + ((u >> 16) & 1u);
    return (unsigned short)(u >> 16);
}
__device__ __forceinline__ float bf2f(unsigned short u) {
    return __uint_as_float(((unsigned)u) << 16);
}
__device__ __forceinline__ float sigm_(float x) {
    float e = __expf(-x);
    return __builtin_amdgcn_rcpf(1.0f + e);
}
__device__ __forceinline__ float tanh_(float x) {
    float e = __expf(2.0f * x);
    return 1.0f - 2.0f * __builtin_amdgcn_rcpf(e + 1.0f);
}

// ---- prep: repack Wcat into kk-major fragment order ----
// uint4 index = (kk*32 + wsub*4 + g)*64 + l ; j = g*256+wsub*32+(l&31),
// k = kk*16 + 8*(l>>5) + e.  One (kk,wsub) group = 4 KB contiguous.
__global__ void prep_wcat(const float* __restrict__ Whh, const float* __restrict__ Wih,
                          unsigned short* __restrict__ dst) {
    int tid = blockIdx.x * 256 + threadIdx.x;   // 49152 total
    int l  = tid & 63;
    int p  = tid >> 6;          // 0..767
    int g    = p & 3;
    int wsub = (p >> 2) & 7;
    int kk   = p >> 5;          // 0..23
    int j  = g * 256 + wsub * 32 + (l & 31);
    int kb = kk * 16 + 8 * (l >> 5);
    unsigned short v[8];
#pragma unroll
    for (int e = 0; e < 8; ++e) {
        int k = kb + e;
        float f = (k < 256) ? Whh[j * 256 + k] : Wih[j * 128 + (k - 256)];
        v[e] = f2bf(f);
    }
    uint4 pk;
    pk.x = (unsigned)v[0] | ((unsigned)v[1] << 16);
    pk.y = (unsigned)v[2] | ((unsigned)v[3] << 16);
    pk.z = (unsigned)v[4] | ((unsigned)v[5] << 16);
    pk.w = (unsigned)v[6] | ((unsigned)v[7] << 16);
    ((uint4*)dst)[tid] = pk;
}

__global__ void prep_wout(const float* __restrict__ Wout, unsigned short* __restrict__ dst) {
    int tid = blockIdx.x * 256 + threadIdx.x;   // 1024 total
    if (tid >= 1024) return;
    int l  = tid & 63;
    int kk = tid >> 6;
    int q  = l & 31;
    int kb = kk * 16 + 8 * (l >> 5);
    unsigned short v[8];
#pragma unroll
    for (int e = 0; e < 8; ++e) {
        float f = (q < 5) ? Wout[q * 256 + kb + e] : 0.0f;
        v[e] = f2bf(f);
    }
    uint4 pk;
    pk.x = (unsigned)v[0] | ((unsigned)v[1] << 16);
    pk.y = (unsigned)v[2] | ((unsigned)v[3] << 16);
    pk.z = (unsigned)v[4] | ((unsigned)v[5] << 16);
    pk.w = (unsigned)v[6] | ((unsigned)v[7] << 16);
    ((uint4*)dst)[tid] = pk;
}

__global__ void prep_bias(const float* __restrict__ bih, const float* __restrict__ bhh,
                          float* __restrict__ dst) {
    int tid = blockIdx.x * 256 + threadIdx.x;
    if (tid < 1024) dst[tid] = bih[tid] + bhh[tid];
}

// ---- main persistent-over-T kernel: 1 block = 64 samples, 8 waves ----
// Phase B is barrier-free: each wave streams its own weight slices through a
// wave-private 3-deep LDS ring, gated by its own counted vmcnt.
__global__ __launch_bounds__(512, 2)
void lstm_main(const float* __restrict__ x_in, const float* __restrict__ h_in,
               const float* __restrict__ c_in, const int* __restrict__ mask,
               const float* __restrict__ W_emb, const float* __restrict__ b_emb,
               const float* __restrict__ b_out,
               const unsigned short* __restrict__ wcat_fr,
               const unsigned short* __restrict__ wout_fr,
               const float* __restrict__ bias_g,
               float* __restrict__ out) {
    __shared__ unsigned short A_lds[64 * KDIM];                    // 48 KB, SWZ
    __shared__ char wstage[8 * 3 * 4096] __attribute__((aligned(16)));  // 96 KB ring
    __shared__ int  m_lds[2][64];

    const int tid   = threadIdx.x;
    const int lane  = tid & 63;
    const int w     = tid >> 6;        // wave 0..7 = unit-block wsub
    const int base  = blockIdx.x * 64;
    const int col   = lane & 31;
    const int khalf = lane >> 5;
    const int ubase = w * 32 + col;

    float c_reg[2][16];                // fp32 c state (exact); h lives as bf16 in A_lds

    // init: h0 -> A_lds (bf16), c0 -> regs
#pragma unroll
    for (int mt = 0; mt < 2; ++mt)
#pragma unroll
        for (int r = 0; r < 16; ++r) {
            int row = mt * 32 + (r & 3) + 8 * (r >> 2) + 4 * khalf;
            float hv = h_in[(size_t)(base + row) * RNN + ubase];
            c_reg[mt][r] = c_in[(size_t)(base + row) * RNN + ubase];
            int byte = row * ROWB + ubase * 2;
            byte ^= SWZ(row);
            A_lds[byte >> 1] = f2bf(hv);
        }

    float bias4[4];
#pragma unroll
    for (int g = 0; g < 4; ++g) bias4[g] = bias_g[g * 256 + ubase];
    const float bo = (col < 5) ? b_out[col] : 0.0f;

    // wave-private weight stream pointers
    const char* wsrc = (const char*)wcat_fr + (size_t)w * 4096 + (size_t)lane * 16; // + kk*32768 + g*1024
    char*       wst  = wstage + w * 12288;                                          // + buf*4096 + g*1024 (uniform)

    // prologue: kk=0 -> buf0, kk=1 -> buf1  (4 loads each)
#pragma unroll
    for (int g = 0; g < 4; ++g) {
        __builtin_amdgcn_global_load_lds(GLB(wsrc + g * 1024),         LDS(wst + g * 1024),        16, 0, 0);
    }
#pragma unroll
    for (int g = 0; g < 4; ++g) {
        __builtin_amdgcn_global_load_lds(GLB(wsrc + 32768 + g * 1024), LDS(wst + 4096 + g * 1024), 16, 0, 0);
    }

    for (int t = 0; t < T_STEPS; ++t) {
        // ---- Phase A: e = relu(x @ W_emb + b_emb) -> A_lds k=256..383; mask -> LDS ----
        {
            int row = tid >> 3;            // 0..63
            int jb  = (tid & 7) * 16;
            const float* xp = x_in + ((size_t)t * NBATCH + base + row) * 2;
            float x0 = xp[0], x1 = xp[1];
#pragma unroll
            for (int jj = 0; jj < 16; jj += 2) {
                int j = jb + jj;
                float e0 = fmaxf(fmaf(x0, W_emb[j],     fmaf(x1, W_emb[128 + j],     b_emb[j])),     0.0f);
                float e1 = fmaxf(fmaf(x0, W_emb[j + 1], fmaf(x1, W_emb[128 + j + 1], b_emb[j + 1])), 0.0f);
                int byte = row * ROWB + 512 + 2 * j;
                byte ^= SWZ(row);
                *(unsigned int*)((char*)A_lds + byte) =
                    (unsigned)f2bf(e0) | ((unsigned)f2bf(e1) << 16);
            }
            if (tid < 64) m_lds[t & 1][tid] = mask[(size_t)t * NBATCH + base + tid];
        }
        BLOCK_SYNC();  // bar1: A_lds + mask ready

        // ---- Phase B: barrier-free pipelined gates (both M-tiles per wave) ----
        f32x16 acc[2][4];
#pragma unroll
        for (int mt = 0; mt < 2; ++mt)
#pragma unroll
            for (int g = 0; g < 4; ++g) {
                f32x16 z;
#pragma unroll
                for (int q = 0; q < 16; ++q) z[q] = bias4[g];
                acc[mt][g] = z;
            }
#pragma unroll 1
        for (int kk = 0; kk < 24; ++kk) {
            // issue kk+2 into ring slot (kk+2)%3 (wraps into next step's kk0/kk1 — same weights)
            int kkn = (kk + 2 < 24) ? (kk + 2) : (kk - 22);
            int bufW = kk + 2; bufW = (bufW >= 3) ? ((bufW >= 24) ? bufW - 24 : bufW % 3) : bufW;
            // (kk+2)%3 computed cheaply: kk%3 cycles 0,1,2 — use lookup-free form below
            bufW = (kk + 2) % 3;
            const char* s0 = wsrc + (size_t)kkn * 32768;
            char*       d0 = wst + bufW * 4096;
#pragma unroll
            for (int g = 0; g < 4; ++g)
                __builtin_amdgcn_global_load_lds(GLB(s0 + g * 1024), LDS(d0 + g * 1024), 16, 0, 0);
            asm volatile("s_waitcnt vmcnt(8)" ::: "memory");  // kk's 4 loads landed (8 newer in flight)

            int bufR = kk % 3;
            const char* wb = wstage + w * 12288 + bufR * 4096 + (size_t)lane * 16;
            bf16x8 f0 = *(const bf16x8*)(wb);
            bf16x8 f1 = *(const bf16x8*)(wb + 1024);
            bf16x8 f2 = *(const bf16x8*)(wb + 2048);
            bf16x8 f3 = *(const bf16x8*)(wb + 3072);
            int row0 = col;
            int b0 = row0 * ROWB + kk * 32 + 16 * khalf; b0 ^= SWZ(row0);
            bf16x8 a0 = *(const bf16x8*)((const char*)A_lds + b0);
            int row1 = 32 + col;
            int b1 = row1 * ROWB + kk * 32 + 16 * khalf; b1 ^= SWZ(row1);
            bf16x8 a1 = *(const bf16x8*)((const char*)A_lds + b1);
            acc[0][0] = __builtin_amdgcn_mfma_f32_32x32x16_bf16(a0, f0, acc[0][0], 0, 0, 0);
            acc[1][0] = __builtin_amdgcn_mfma_f32_32x32x16_bf16(a1, f0, acc[1][0], 0, 0, 0);
            acc[0][1] = __builtin_amdgcn_mfma_f32_32x32x16_bf16(a0, f1, acc[0][1], 0, 0, 0);
            acc[1][1] = __builtin_amdgcn_mfma_f32_32x32x16_bf16(a1, f1, acc[1][1], 0, 0, 0);
            acc[0][2] = __builtin_amdgcn_mfma_f32_32x32x16_bf16(a0, f2, acc[0][2], 0, 0, 0);
            acc[1][2] = __builtin_amdgcn_mfma_f32_32x32x16_bf16(a1, f2, acc[1][2], 0, 0, 0);
            acc[0][3] = __builtin_amdgcn_mfma_f32_32x32x16_bf16(a0, f3, acc[0][3], 0, 0, 0);
            acc[1][3] = __builtin_amdgcn_mfma_f32_32x32x16_bf16(a1, f3, acc[1][3], 0, 0, 0);
        }
        BLOCK_SYNC();  // bar2: all A_lds reads done before h overwrite

        // ---- Phase C: elementwise LSTM update (fp32); masked rows keep old bf16 h ----
#pragma unroll
        for (int mt = 0; mt < 2; ++mt)
#pragma unroll
            for (int r = 0; r < 16; ++r) {
                int row = mt * 32 + (r & 3) + 8 * (r >> 2) + 4 * khalf;
                float iv = sigm_(acc[mt][0][r]);
                float fv = sigm_(acc[mt][1][r]);
                float gv = tanh_(acc[mt][2][r]);
                float ov = sigm_(acc[mt][3][r]);
                float cn = fmaf(fv, c_reg[mt][r], iv * gv);
                float hn = ov * tanh_(cn);
                int m = m_lds[t & 1][row];
                if (m) {
                    c_reg[mt][r] = cn;
                    int byte = row * ROWB + ubase * 2;
                    byte ^= SWZ(row);
                    A_lds[byte >> 1] = f2bf(hn);
                }
            }
        BLOCK_SYNC();  // bar3: new h visible

        // ---- Phase D: out = h @ Wout^T + b_out (waves 0,1; 32-col padded tile) ----
        if (w < 2) {
            f32x16 oacc;
#pragma unroll
            for (int q = 0; q < 16; ++q) oacc[q] = bo;
#pragma unroll
            for (int kk = 0; kk < 16; ++kk) {
                int row = w * 32 + col;
                int b0 = row * ROWB + kk * 32 + 16 * khalf; b0 ^= SWZ(row);
                bf16x8 a = *(const bf16x8*)((const char*)A_lds + b0);
                bf16x8 bfr = *(const bf16x8*)(wout_fr + ((size_t)kk * 64 + lane) * 8);
                oacc = __builtin_amdgcn_mfma_f32_32x32x16_bf16(a, bfr, oacc, 0, 0, 0);
            }
            if (col < 5) {
#pragma unroll
                for (int r = 0; r < 16; ++r) {
                    int row = w * 32 + (r & 3) + 8 * (r >> 2) + 4 * khalf;
                    int m = m_lds[t & 1][row];
                    out[((size_t)t * NBATCH + base + row) * 5 + col] = m ? oacc[r] : 0.0f;
                }
            }
        }
        // no barrier: D reads h-region (k<256); next A writes e-region + other m_lds slot
    }

    asm volatile("s_waitcnt vmcnt(0)" ::: "memory");  // retire in-flight prefetch

    // ---- final states: h from A_lds (bf16), c from regs (fp32) ----
    float* hout = out + (size_t)T_STEPS * NBATCH * 5;
    float* cout = hout + (size_t)NBATCH * RNN;
#pragma unroll
    for (int mt = 0; mt < 2; ++mt)
#pragma unroll
        for (int r = 0; r < 16; ++r) {
            int row = mt * 32 + (r & 3) + 8 * (r >> 2) + 4 * khalf;
            int byte = row * ROWB + ubase * 2;
            byte ^= SWZ(row);
            hout[(size_t)(base + row) * RNN + ubase] = bf2f(A_lds[byte >> 1]);
            cout[(size_t)(base + row) * RNN + ubase] = c_reg[mt][r];
        }
}

extern "C" void kernel_launch(void* const* d_in, const int* in_sizes, int n_in,
                              void* d_out, int out_size, void* d_ws, size_t ws_size,
                              hipStream_t stream) {
    (void)in_sizes; (void)n_in; (void)out_size; (void)ws_size;
    const float* x_in = (const float*)d_in[0];
    const float* h0   = (const float*)d_in[1];
    const float* c0   = (const float*)d_in[2];
    const int*   mk   = (const int*)d_in[3];
    const float* Wemb = (const float*)d_in[4];
    const float* bemb = (const float*)d_in[5];
    const float* Wih  = (const float*)d_in[6];
    const float* bih  = (const float*)d_in[7];
    const float* Whh  = (const float*)d_in[8];
    const float* bhh  = (const float*)d_in[9];
    const float* Wout = (const float*)d_in[10];
    const float* bout = (const float*)d_in[11];

    unsigned short* wcat = (unsigned short*)d_ws;        // 768 KB, kk-major fragments
    unsigned short* wouf = wcat + 393216;                // 8192 bf16
    float*          bsg  = (float*)(wouf + 8192);        // 1024 f32

    prep_wcat<<<192, 256, 0, stream>>>(Whh, Wih, wcat);
    prep_wout<<<4, 256, 0, stream>>>(Wout, wouf);
    prep_bias<<<4, 256, 0, stream>>>(bih, bhh, bsg);

    float* outp = (float*)d_out;
    lstm_main<<<1024, 512, 0, stream>>>(x_in, h0, c0, mk, Wemb, bemb, bout,
                                        wcat, wouf, bsg, outp);
}

// Round 7
// 1796.414 us; speedup vs baseline: 18.5529x; 1.2971x over previous
//
#include <hip/hip_runtime.h>

#define T_STEPS 19
#define NBATCH  65536
#define RNN     256
#define EMB     128
#define KDIM    384   // RNN + EMB
#define ROWB    768   // KDIM * 2 bytes (LDS row stride)
#define SWZ(row) (((row) & 15) << 4)

typedef __bf16 bf16x8 __attribute__((ext_vector_type(8)));
typedef float  f32x4  __attribute__((ext_vector_type(4)));

#define BLOCK_SYNC() asm volatile("s_waitcnt lgkmcnt(0)\n\ts_barrier" ::: "memory")

__device__ __forceinline__ unsigned short f2bf(float f) {
    unsigned u = __float_as_uint(f);
    u += 0x7fffu + ((u >> 16) & 1u);
    return (unsigned short)(u >> 16);
}
__device__ __forceinline__ float bf2f(unsigned short u) {
    return __uint_as_float(((unsigned)u) << 16);
}
__device__ __forceinline__ float sigm_(float x) {
    float e = __expf(-x);
    return __builtin_amdgcn_rcpf(1.0f + e);
}
__device__ __forceinline__ float tanh_(float x) {
    float e = __expf(2.0f * x);
    return 1.0f - 2.0f * __builtin_amdgcn_rcpf(e + 1.0f);
}

// ---- prep: Wcat fragments for 16x16x32 MFMA, wave-private slices ----
// uint4 idx = ((w*12 + kk)*4 + g)*64 + l
//   j = g*256 + w*16 + (l&15)   (gate-output column)
//   k = kk*32 + (l>>4)*8 + e
__global__ void prep_wcat(const float* __restrict__ Whh, const float* __restrict__ Wih,
                          unsigned short* __restrict__ dst) {
    int tid = blockIdx.x * 256 + threadIdx.x;   // 49152 total
    int l   = tid & 63;
    int p   = tid >> 6;          // 0..767 = (w*12+kk)*4+g
    int g   = p & 3;
    int kkw = p >> 2;
    int kk  = kkw % 12;
    int w   = kkw / 12;          // 0..15
    int j   = g * 256 + w * 16 + (l & 15);
    int kb  = kk * 32 + (l >> 4) * 8;
    unsigned short v[8];
#pragma unroll
    for (int e = 0; e < 8; ++e) {
        int k = kb + e;
        float f = (k < 256) ? Whh[j * 256 + k] : Wih[j * 128 + (k - 256)];
        v[e] = f2bf(f);
    }
    uint4 pk;
    pk.x = (unsigned)v[0] | ((unsigned)v[1] << 16);
    pk.y = (unsigned)v[2] | ((unsigned)v[3] << 16);
    pk.z = (unsigned)v[4] | ((unsigned)v[5] << 16);
    pk.w = (unsigned)v[6] | ((unsigned)v[7] << 16);
    ((uint4*)dst)[tid] = pk;
}

// ---- prep: Wout fragments for 16x16x32 (16-col tile, cols 5..15 zero) ----
// uint4 idx = kk*64 + l ; q = l&15, k = kk*32 + (l>>4)*8 + e ; kk 0..7
__global__ void prep_wout(const float* __restrict__ Wout, unsigned short* __restrict__ dst) {
    int tid = blockIdx.x * 256 + threadIdx.x;   // 512 total
    if (tid >= 512) return;
    int l  = tid & 63;
    int kk = tid >> 6;
    int q  = l & 15;
    int kb = kk * 32 + (l >> 4) * 8;
    unsigned short v[8];
#pragma unroll
    for (int e = 0; e < 8; ++e) {
        float f = (q < 5) ? Wout[q * 256 + kb + e] : 0.0f;
        v[e] = f2bf(f);
    }
    uint4 pk;
    pk.x = (unsigned)v[0] | ((unsigned)v[1] << 16);
    pk.y = (unsigned)v[2] | ((unsigned)v[3] << 16);
    pk.z = (unsigned)v[4] | ((unsigned)v[5] << 16);
    pk.w = (unsigned)v[6] | ((unsigned)v[7] << 16);
    ((uint4*)dst)[tid] = pk;
}

__global__ void prep_bias(const float* __restrict__ bih, const float* __restrict__ bhh,
                          float* __restrict__ dst) {
    int tid = blockIdx.x * 256 + threadIdx.x;
    if (tid < 1024) dst[tid] = bih[tid] + bhh[tid];
}

// ---- main persistent-over-T kernel: 1 block = 64 samples, 16 waves, 4 waves/SIMD ----
// Wave tile: 64 rows x 16 units x 4 gates via mfma 16x16x32 (acc = 64 regs).
// Weights stream global->VGPR, wave-private, depth-2 rotating buffers.
__global__ __launch_bounds__(1024, 4)
void lstm_main(const float* __restrict__ x_in, const float* __restrict__ h_in,
               const float* __restrict__ c_in, const int* __restrict__ mask,
               const float* __restrict__ W_emb, const float* __restrict__ b_emb,
               const float* __restrict__ b_out,
               const unsigned short* __restrict__ wcat_fr,
               const unsigned short* __restrict__ wout_fr,
               const float* __restrict__ bias_g,
               float* __restrict__ out) {
    __shared__ unsigned short A_lds[64 * KDIM];   // 48 KB, XOR-swizzled
    __shared__ float c_lds[64 * RNN];             // 64 KB fp32 c state
    __shared__ float we_lds[384];                 // W_emb(256) + b_emb(128)
    __shared__ int   m_lds[2][64];

    const int tid  = threadIdx.x;
    const int lane = tid & 63;
    const int w    = tid >> 6;         // wave 0..15 = unit-block
    const int base = blockIdx.x * 64;
    const int csub = lane & 15;        // col within 16-wide tile
    const int kq   = lane >> 2 >> 2;   // lane>>4: 0..3
    const int unit = w * 16 + csub;    // this lane's gate-output unit

    // init: h0 -> A_lds (bf16), c0 -> c_lds (fp32); per thread 16 (row,unit) pairs
#pragma unroll
    for (int m = 0; m < 4; ++m)
#pragma unroll
        for (int r = 0; r < 4; ++r) {
            int row = m * 16 + kq * 4 + r;
            float hv = h_in[(size_t)(base + row) * RNN + unit];
            c_lds[row * RNN + unit] = c_in[(size_t)(base + row) * RNN + unit];
            int byte = row * ROWB + unit * 2;
            byte ^= SWZ(row);
            A_lds[byte >> 1] = f2bf(hv);
        }
    if (tid < 384) we_lds[tid] = (tid < 256) ? W_emb[tid] : b_emb[tid - 256];

    float bias4[4];
#pragma unroll
    for (int g = 0; g < 4; ++g) bias4[g] = bias_g[g * 256 + unit];
    const float bo = (csub < 5) ? b_out[csub] : 0.0f;

    const uint4* wfp = (const uint4*)wcat_fr + (size_t)w * (12 * 4 * 64) + lane;
    const uint4* wop = (const uint4*)wout_fr + lane;

    // persistent depth-2 weight pipeline (regs), wraps across steps
    bf16x8 bA[4], bB[4];
#pragma unroll
    for (int g = 0; g < 4; ++g) bA[g] = *(const bf16x8*)(wfp + (0 * 4 + g) * 64);
#pragma unroll
    for (int g = 0; g < 4; ++g) bB[g] = *(const bf16x8*)(wfp + (1 * 4 + g) * 64);

    BLOCK_SYNC();  // init LDS (h, c, we_lds) visible

    for (int t = 0; t < T_STEPS; ++t) {
        // ---- Phase A: e = relu(x @ W_emb + b_emb) -> A_lds k=256..383 ----
        {
            int row = tid >> 4;            // 0..63
            int jc  = (tid & 15) * 8;      // 8 consecutive j's
            const float* xp = x_in + ((size_t)t * NBATCH + base + row) * 2;
            float x0 = xp[0], x1 = xp[1];
            unsigned pk[4];
#pragma unroll
            for (int e = 0; e < 8; e += 2) {
                int j = jc + e;
                float e0 = fmaxf(fmaf(x0, we_lds[j],     fmaf(x1, we_lds[128 + j],     we_lds[256 + j])),     0.0f);
                float e1 = fmaxf(fmaf(x0, we_lds[j + 1], fmaf(x1, we_lds[128 + j + 1], we_lds[256 + j + 1])), 0.0f);
                pk[e >> 1] = (unsigned)f2bf(e0) | ((unsigned)f2bf(e1) << 16);
            }
            int byte = row * ROWB + 512 + 2 * jc;
            byte ^= SWZ(row);
            *(uint4*)((char*)A_lds + byte) = make_uint4(pk[0], pk[1], pk[2], pk[3]);
            if (tid < 64) m_lds[t & 1][tid] = mask[(size_t)t * NBATCH + base + tid];
        }
        BLOCK_SYNC();  // bar1: A_lds + mask ready

        // ---- Phase B: gates for 64 rows x 16 units x 4 gates (12 kk-slices of K=32) ----
        f32x4 acc[4][4];
#pragma unroll
        for (int m = 0; m < 4; ++m)
#pragma unroll
            for (int g = 0; g < 4; ++g) {
                f32x4 z = {bias4[g], bias4[g], bias4[g], bias4[g]};
                acc[m][g] = z;
            }
#pragma unroll 1
        for (int kp = 0; kp < 6; ++kp) {
            int kk0 = kp * 2;
            // even half: consume bA (slice kk0), refill with kk0+2
            {
#pragma unroll
                for (int m = 0; m < 4; ++m) {
                    int row = m * 16 + csub;
                    int byte = row * ROWB + kk0 * 64 + kq * 16;
                    byte ^= SWZ(row);
                    bf16x8 a = *(const bf16x8*)((const char*)A_lds + byte);
                    acc[m][0] = __builtin_amdgcn_mfma_f32_16x16x32_bf16(a, bA[0], acc[m][0], 0, 0, 0);
                    acc[m][1] = __builtin_amdgcn_mfma_f32_16x16x32_bf16(a, bA[1], acc[m][1], 0, 0, 0);
                    acc[m][2] = __builtin_amdgcn_mfma_f32_16x16x32_bf16(a, bA[2], acc[m][2], 0, 0, 0);
                    acc[m][3] = __builtin_amdgcn_mfma_f32_16x16x32_bf16(a, bA[3], acc[m][3], 0, 0, 0);
                }
                int kn = kk0 + 2; if (kn >= 12) kn -= 12;   // wraps into next step (same weights)
#pragma unroll
                for (int g = 0; g < 4; ++g)
                    bA[g] = *(const bf16x8*)(wfp + (kn * 4 + g) * 64);
            }
            // odd half: consume bB (slice kk0+1), refill with kk0+3
            {
                int kk1 = kk0 + 1;
#pragma unroll
                for (int m = 0; m < 4; ++m) {
                    int row = m * 16 + csub;
                    int byte = row * ROWB + kk1 * 64 + kq * 16;
                    byte ^= SWZ(row);
                    bf16x8 a = *(const bf16x8*)((const char*)A_lds + byte);
                    acc[m][0] = __builtin_amdgcn_mfma_f32_16x16x32_bf16(a, bB[0], acc[m][0], 0, 0, 0);
                    acc[m][1] = __builtin_amdgcn_mfma_f32_16x16x32_bf16(a, bB[1], acc[m][1], 0, 0, 0);
                    acc[m][2] = __builtin_amdgcn_mfma_f32_16x16x32_bf16(a, bB[2], acc[m][2], 0, 0, 0);
                    acc[m][3] = __builtin_amdgcn_mfma_f32_16x16x32_bf16(a, bB[3], acc[m][3], 0, 0, 0);
                }
                int kn = kk1 + 2; if (kn >= 12) kn -= 12;
#pragma unroll
                for (int g = 0; g < 4; ++g)
                    bB[g] = *(const bf16x8*)(wfp + (kn * 4 + g) * 64);
            }
        }
        BLOCK_SYNC();  // bar2: all A_lds reads done before h overwrite

        // ---- Phase C: elementwise LSTM update; c in LDS, h as bf16 in A_lds ----
#pragma unroll
        for (int m = 0; m < 4; ++m)
#pragma unroll
            for (int r = 0; r < 4; ++r) {
                int row = m * 16 + kq * 4 + r;
                float cv = c_lds[row * RNN + unit];
                float iv = sigm_(acc[m][0][r]);
                float fv = sigm_(acc[m][1][r]);
                float gv = tanh_(acc[m][2][r]);
                float ov = sigm_(acc[m][3][r]);
                float cn = fmaf(fv, cv, iv * gv);
                float hn = ov * tanh_(cn);
                if (m_lds[t & 1][row]) {
                    c_lds[row * RNN + unit] = cn;
                    int byte = row * ROWB + unit * 2;
                    byte ^= SWZ(row);
                    A_lds[byte >> 1] = f2bf(hn);
                }
            }
        BLOCK_SYNC();  // bar3: new h visible

        // ---- Phase D: out = h @ Wout^T + b_out (waves 0..3, m-subtile = w) ----
        if (w < 4) {
            f32x4 oacc = {bo, bo, bo, bo};
#pragma unroll
            for (int kk = 0; kk < 8; ++kk) {
                int row = w * 16 + csub;
                int byte = row * ROWB + kk * 64 + kq * 16;
                byte ^= SWZ(row);
                bf16x8 a  = *(const bf16x8*)((const char*)A_lds + byte);
                bf16x8 bw = *(const bf16x8*)(wop + kk * 64);
                oacc = __builtin_amdgcn_mfma_f32_16x16x32_bf16(a, bw, oacc, 0, 0, 0);
            }
            if (csub < 5) {
#pragma unroll
                for (int r = 0; r < 4; ++r) {
                    int row = w * 16 + kq * 4 + r;
                    int m = m_lds[t & 1][row];
                    out[((size_t)t * NBATCH + base + row) * 5 + csub] = m ? oacc[r] : 0.0f;
                }
            }
        }
        // no barrier: D reads h-region (k<256) + m_lds[t&1]; next A writes e-region
        // (k>=256) + m_lds[(t+1)&1] — disjoint. C(t+1) writes are behind bar1+bar2.
    }

    // ---- final states: h from A_lds (bf16), c from c_lds (fp32) ----
    float* hout = out + (size_t)T_STEPS * NBATCH * 5;
    float* cout = hout + (size_t)NBATCH * RNN;
#pragma unroll
    for (int m = 0; m < 4; ++m)
#pragma unroll
        for (int r = 0; r < 4; ++r) {
            int row = m * 16 + kq * 4 + r;
            int byte = row * ROWB + unit * 2;
            byte ^= SWZ(row);
            hout[(size_t)(base + row) * RNN + unit] = bf2f(A_lds[byte >> 1]);
            cout[(size_t)(base + row) * RNN + unit] = c_lds[row * RNN + unit];
        }
}

extern "C" void kernel_launch(void* const* d_in, const int* in_sizes, int n_in,
                              void* d_out, int out_size, void* d_ws, size_t ws_size,
                              hipStream_t stream) {
    (void)in_sizes; (void)n_in; (void)out_size; (void)ws_size;
    const float* x_in = (const float*)d_in[0];
    const float* h0   = (const float*)d_in[1];
    const float* c0   = (const float*)d_in[2];
    const int*   mk   = (const int*)d_in[3];
    const float* Wemb = (const float*)d_in[4];
    const float* bemb = (const float*)d_in[5];
    const float* Wih  = (const float*)d_in[6];
    const float* bih  = (const float*)d_in[7];
    const float* Whh  = (const float*)d_in[8];
    const float* bhh  = (const float*)d_in[9];
    const float* Wout = (const float*)d_in[10];
    const float* bout = (const float*)d_in[11];

    unsigned short* wcat = (unsigned short*)d_ws;        // 49152 uint4 = 768 KB
    unsigned short* wouf = wcat + 393216;                // 512 uint4 = 8 KB
    float*          bsg  = (float*)(wouf + 4096);        // 1024 f32

    prep_wcat<<<192, 256, 0, stream>>>(Whh, Wih, wcat);
    prep_wout<<<2, 256, 0, stream>>>(Wout, wouf);
    prep_bias<<<4, 256, 0, stream>>>(bih, bhh, bsg);

    float* outp = (float*)d_out;
    lstm_main<<<1024, 1024, 0, stream>>>(x_in, h0, c0, mk, Wemb, bemb, bout,
                                         wcat, wouf, bsg, outp);
}